// Round 6
// baseline (8280.725 us; speedup 1.0000x reference)
//
#include <hip/hip_runtime.h>
#include <math.h>

// (B,N,D,H,HD,M) = (4,512,768,12,64,3072)
#define NTOK   2048
#define DDIM   768
#define NHEAD  12
#define HDIM   64
#define MMEM   3072
#define C2     1536
#define NSTEPS 12
#define ALPHA  0.125f
#define BETA   0.125f
#define LNEPS  1e-5f

// ---------------------------------------------------------------------------
// LayerNorm forward: x -> g, xhat, rstd.  One block per row (768 elems).
// ---------------------------------------------------------------------------
__global__ __launch_bounds__(256) void ln_fwd(const float* __restrict__ x,
                                              const float* __restrict__ gamma,
                                              const float* __restrict__ delta,
                                              float* __restrict__ g,
                                              float* __restrict__ xhat,
                                              float* __restrict__ rstd) {
    const int row = blockIdx.x;
    const int tid = threadIdx.x;
    const float* xr = x + (size_t)row * DDIM;
    float v[3];
    v[0] = xr[tid]; v[1] = xr[tid + 256]; v[2] = xr[tid + 512];
    float s1 = v[0] + v[1] + v[2];
    float s2 = v[0]*v[0] + v[1]*v[1] + v[2]*v[2];
    __shared__ float sb1[4], sb2[4];
    for (int off = 32; off > 0; off >>= 1) {
        s1 += __shfl_down(s1, off, 64);
        s2 += __shfl_down(s2, off, 64);
    }
    const int lane = tid & 63, wid = tid >> 6;
    if (lane == 0) { sb1[wid] = s1; sb2[wid] = s2; }
    __syncthreads();
    s1 = sb1[0] + sb1[1] + sb1[2] + sb1[3];
    s2 = sb2[0] + sb2[1] + sb2[2] + sb2[3];
    const float mu  = s1 * (1.0f / DDIM);
    const float var = s2 * (1.0f / DDIM) - mu * mu;
    const float rs  = 1.0f / sqrtf(var + LNEPS);
    if (tid == 0) rstd[row] = rs;
    #pragma unroll
    for (int c = 0; c < 3; ++c) {
        const int d = tid + c * 256;
        const float xh = (v[c] - mu) * rs;
        xhat[(size_t)row * DDIM + d] = xh;
        g[(size_t)row * DDIM + d]   = gamma[d] * xh + delta[d];
    }
}

// ---------------------------------------------------------------------------
// Generic fp32 GEMM, 64x64 C-tile, K-tile 16, 4x4 per thread, float4 LDS reads.
// C[m,n] = sum_k A[m,k] * B(k,n)   (A row-major, lda=K)
// BMODE 0: B(k,n) = B0[k*Nn + n]                      (xi row-major, dg+=R@xi)
// BMODE 1: B(k,n) = W[h*49152 + k*64 + e], n=q/k col  (qk fwd; W, h, e per n)
// BMODE 2: B(k,n) = B0[n*768 + k]                     (xi^T; R = g @ xi^T)
// BMODE 3: B(k,n) = W[h*49152 + n*64 + e], k=q/k col  (dg att pullback)
// NOTE: DDIM=768 is NOT a power of two — use explicit subtract, never &(DDIM-1).
// ---------------------------------------------------------------------------
template<int BMODE, bool RELU, bool ACCUM>
__global__ __launch_bounds__(256) void gemm_k(const float* __restrict__ A,
                                              const float* __restrict__ B0,
                                              const float* __restrict__ B1,
                                              float* __restrict__ C,
                                              int M, int Nn, int K) {
    __shared__ __attribute__((aligned(16))) float As[16][68]; // [k][m]
    __shared__ __attribute__((aligned(16))) float Bs[16][68]; // [k][n]
    const int tid = threadIdx.x;
    const int tx = tid & 15, ty = tid >> 4;
    const int bm = blockIdx.y * 64, bn = blockIdx.x * 64;
    float acc[4][4] = {};
    for (int k0 = 0; k0 < K; k0 += 16) {
        {   // A tile (transposed store into LDS)
            const int kk = tid & 15;
            #pragma unroll
            for (int p = 0; p < 4; ++p) {
                const int mm = (tid >> 4) + p * 16;
                As[kk][mm] = A[(size_t)(bm + mm) * K + k0 + kk];
            }
        }
        if (BMODE == 0) {
            const int nn = tid & 63;
            #pragma unroll
            for (int p = 0; p < 4; ++p) {
                const int kk = (tid >> 6) + p * 4;
                Bs[kk][nn] = B0[(size_t)(k0 + kk) * Nn + bn + nn];
            }
        } else if (BMODE == 1) {
            const int nn = tid & 63;
            const int n = bn + nn;
            const float* W = (n < DDIM) ? B0 : B1;
            const int nh = (n < DDIM) ? n : n - DDIM;   // 768 not pow2: no mask!
            const float* base = W + (size_t)(nh >> 6) * (DDIM * HDIM) + (nh & 63);
            #pragma unroll
            for (int p = 0; p < 4; ++p) {
                const int kk = (tid >> 6) + p * 4;
                Bs[kk][nn] = base[(size_t)(k0 + kk) * HDIM];
            }
        } else if (BMODE == 2) {
            const int kk = tid & 15;
            #pragma unroll
            for (int p = 0; p < 4; ++p) {
                const int nn = (tid >> 4) + p * 16;
                Bs[kk][nn] = B0[(size_t)(bn + nn) * DDIM + k0 + kk];
            }
        } else { // BMODE 3
            const int kk = tid & 15;
            const int k = k0 + kk;
            const float* W = (k < DDIM) ? B0 : B1;
            const int kh = (k < DDIM) ? k : k - DDIM;   // 768 not pow2: no mask!
            const float* base = W + (size_t)(kh >> 6) * (DDIM * HDIM) + (kh & 63);
            #pragma unroll
            for (int p = 0; p < 4; ++p) {
                const int nn = (tid >> 4) + p * 16;
                Bs[kk][nn] = base[(size_t)(bn + nn) * HDIM];
            }
        }
        __syncthreads();
        #pragma unroll
        for (int kk = 0; kk < 16; ++kk) {
            const float4 a4 = *(const float4*)&As[kk][ty * 4];
            const float4 b4 = *(const float4*)&Bs[kk][tx * 4];
            const float a[4] = {a4.x, a4.y, a4.z, a4.w};
            const float b[4] = {b4.x, b4.y, b4.z, b4.w};
            #pragma unroll
            for (int i = 0; i < 4; ++i)
                #pragma unroll
                for (int j = 0; j < 4; ++j)
                    acc[i][j] += a[i] * b[j];
        }
        __syncthreads();
    }
    #pragma unroll
    for (int i = 0; i < 4; ++i) {
        const size_t off = (size_t)(bm + ty * 4 + i) * Nn + bn + tx * 4;
        float4 v = make_float4(acc[i][0], acc[i][1], acc[i][2], acc[i][3]);
        if (RELU) {
            v.x = fmaxf(v.x, 0.f); v.y = fmaxf(v.y, 0.f);
            v.z = fmaxf(v.z, 0.f); v.w = fmaxf(v.w, 0.f);
        }
        if (ACCUM) {
            const float4 o = *(const float4*)&C[off];
            v.x += o.x; v.y += o.y; v.z += o.z; v.w += o.w;
        }
        *(float4*)&C[off] = v;
    }
}

// ---------------------------------------------------------------------------
// Attention pass A: per (b,h,i-tile of 64): online softmax over j,
// dq_store[i,e] = sum_j p_ij k[j,e]  (positive; true grad is -dq_store),
// lse[i] = m + log(l).
// q[b,n,h,e] = qk[(b*512+n)*1536 + h*64 + e], k at +768.
// ---------------------------------------------------------------------------
__global__ __launch_bounds__(256) void attn_dq(const float* __restrict__ qk,
                                               float* __restrict__ dqk,
                                               float* __restrict__ lse) {
    __shared__ __attribute__((aligned(16))) float Qs[64][68];
    __shared__ __attribute__((aligned(16))) float Ks[64][68];
    __shared__ __attribute__((aligned(16))) float Ps[64][68];
    const int tid = threadIdx.x;
    const int tx = tid & 15, ty = tid >> 4;
    const int it = blockIdx.x * 64;
    const int h = blockIdx.y, b = blockIdx.z;
    const float* qbase = qk + (size_t)b * 512 * C2 + h * HDIM;
    const float* kbase = qbase + DDIM;
    #pragma unroll 4
    for (int p = 0; p < 16; ++p) {
        const int r = (tid >> 6) + p * 4, e = tid & 63;
        Qs[r][e] = qbase[(size_t)(it + r) * C2 + e];
    }
    float m[4], l[4], acc[4][4];
    #pragma unroll
    for (int i = 0; i < 4; ++i) {
        m[i] = -1e30f; l[i] = 0.f;
        #pragma unroll
        for (int j = 0; j < 4; ++j) acc[i][j] = 0.f;
    }
    for (int jt = 0; jt < 512; jt += 64) {
        __syncthreads();
        #pragma unroll 4
        for (int p = 0; p < 16; ++p) {
            const int r = (tid >> 6) + p * 4, e = tid & 63;
            Ks[r][e] = kbase[(size_t)(jt + r) * C2 + e];
        }
        __syncthreads();
        float s[4][4];
        #pragma unroll
        for (int i = 0; i < 4; ++i)
            #pragma unroll
            for (int j = 0; j < 4; ++j) s[i][j] = 0.f;
        #pragma unroll 4
        for (int e4 = 0; e4 < 16; ++e4) {
            float4 a[4], bb[4];
            #pragma unroll
            for (int i = 0; i < 4; ++i) a[i]  = *(const float4*)&Qs[ty * 4 + i][e4 * 4];
            #pragma unroll
            for (int j = 0; j < 4; ++j) bb[j] = *(const float4*)&Ks[tx * 4 + j][e4 * 4];
            #pragma unroll
            for (int i = 0; i < 4; ++i)
                #pragma unroll
                for (int j = 0; j < 4; ++j)
                    s[i][j] += a[i].x * bb[j].x + a[i].y * bb[j].y
                             + a[i].z * bb[j].z + a[i].w * bb[j].w;
        }
        #pragma unroll
        for (int i = 0; i < 4; ++i) {
            float rmax = -1e30f;
            #pragma unroll
            for (int j = 0; j < 4; ++j) { s[i][j] *= BETA; rmax = fmaxf(rmax, s[i][j]); }
            #pragma unroll
            for (int off = 1; off < 16; off <<= 1) rmax = fmaxf(rmax, __shfl_xor(rmax, off, 16));
            const float mnew = fmaxf(m[i], rmax);
            const float sc = expf(m[i] - mnew);
            float rsum = 0.f;
            #pragma unroll
            for (int j = 0; j < 4; ++j) { s[i][j] = expf(s[i][j] - mnew); rsum += s[i][j]; }
            #pragma unroll
            for (int off = 1; off < 16; off <<= 1) rsum += __shfl_xor(rsum, off, 16);
            l[i] = l[i] * sc + rsum;
            m[i] = mnew;
            #pragma unroll
            for (int j = 0; j < 4; ++j) acc[i][j] *= sc;
            #pragma unroll
            for (int j = 0; j < 4; ++j) Ps[ty * 4 + i][tx * 4 + j] = s[i][j];
        }
        __syncthreads();
        // acc[i][e] += sum_jj Ps[row][jj] * Ks[jj][e], e = tx*4+j
        #pragma unroll 4
        for (int jj4 = 0; jj4 < 16; ++jj4) {
            float4 pv[4];
            #pragma unroll
            for (int i = 0; i < 4; ++i) pv[i] = *(const float4*)&Ps[ty * 4 + i][jj4 * 4];
            #pragma unroll
            for (int u = 0; u < 4; ++u) {
                const float4 kv = *(const float4*)&Ks[jj4 * 4 + u][tx * 4];
                #pragma unroll
                for (int i = 0; i < 4; ++i) {
                    const float pw = (u == 0) ? pv[i].x : (u == 1) ? pv[i].y
                                   : (u == 2) ? pv[i].z : pv[i].w;
                    acc[i][0] += pw * kv.x; acc[i][1] += pw * kv.y;
                    acc[i][2] += pw * kv.z; acc[i][3] += pw * kv.w;
                }
            }
        }
    }
    float* dqbase = dqk + (size_t)b * 512 * C2 + h * HDIM;
    #pragma unroll
    for (int i = 0; i < 4; ++i) {
        const float inv = 1.0f / l[i];
        const float4 v = make_float4(acc[i][0] * inv, acc[i][1] * inv,
                                     acc[i][2] * inv, acc[i][3] * inv);
        *(float4*)&dqbase[(size_t)(it + ty * 4 + i) * C2 + tx * 4] = v;
        if (tx == 0)
            lse[(size_t)(b * NHEAD + h) * 512 + it + ty * 4 + i] = m[i] + logf(l[i]);
    }
}

// ---------------------------------------------------------------------------
// Attention pass B: dk_store[j,e] = sum_i p_ij q[i,e], p from stored lse.
// ---------------------------------------------------------------------------
__global__ __launch_bounds__(256) void attn_dk(const float* __restrict__ qk,
                                               float* __restrict__ dqk,
                                               const float* __restrict__ lse) {
    __shared__ __attribute__((aligned(16))) float Ks[64][68];
    __shared__ __attribute__((aligned(16))) float Qs[64][68];
    __shared__ __attribute__((aligned(16))) float Ps[64][68];
    __shared__ float Ls[64];
    const int tid = threadIdx.x;
    const int tx = tid & 15, ty = tid >> 4;
    const int jt = blockIdx.x * 64;
    const int h = blockIdx.y, b = blockIdx.z;
    const float* qbase = qk + (size_t)b * 512 * C2 + h * HDIM;
    const float* kbase = qbase + DDIM;
    #pragma unroll 4
    for (int p = 0; p < 16; ++p) {
        const int r = (tid >> 6) + p * 4, e = tid & 63;
        Ks[r][e] = kbase[(size_t)(jt + r) * C2 + e];
    }
    float acc[4][4];
    #pragma unroll
    for (int i = 0; i < 4; ++i)
        #pragma unroll
        for (int j = 0; j < 4; ++j) acc[i][j] = 0.f;
    for (int it = 0; it < 512; it += 64) {
        __syncthreads();
        #pragma unroll 4
        for (int p = 0; p < 16; ++p) {
            const int r = (tid >> 6) + p * 4, e = tid & 63;
            Qs[r][e] = qbase[(size_t)(it + r) * C2 + e];
        }
        if (tid < 64) Ls[tid] = lse[(size_t)(b * NHEAD + h) * 512 + it + tid];
        __syncthreads();
        float s[4][4];
        #pragma unroll
        for (int i = 0; i < 4; ++i)
            #pragma unroll
            for (int j = 0; j < 4; ++j) s[i][j] = 0.f;
        #pragma unroll 4
        for (int e4 = 0; e4 < 16; ++e4) {
            float4 a[4], bb[4];
            #pragma unroll
            for (int i = 0; i < 4; ++i) a[i]  = *(const float4*)&Ks[ty * 4 + i][e4 * 4];
            #pragma unroll
            for (int j = 0; j < 4; ++j) bb[j] = *(const float4*)&Qs[tx * 4 + j][e4 * 4];
            #pragma unroll
            for (int i = 0; i < 4; ++i)
                #pragma unroll
                for (int j = 0; j < 4; ++j)
                    s[i][j] += a[i].x * bb[j].x + a[i].y * bb[j].y
                             + a[i].z * bb[j].z + a[i].w * bb[j].w;
        }
        #pragma unroll
        for (int i = 0; i < 4; ++i)
            #pragma unroll
            for (int j = 0; j < 4; ++j) {
                const float p = expf(s[i][j] * BETA - Ls[tx * 4 + j]);
                Ps[ty * 4 + i][tx * 4 + j] = p;
            }
        __syncthreads();
        #pragma unroll 4
        for (int ii4 = 0; ii4 < 16; ++ii4) {
            float4 pv[4];
            #pragma unroll
            for (int i = 0; i < 4; ++i) pv[i] = *(const float4*)&Ps[ty * 4 + i][ii4 * 4];
            #pragma unroll
            for (int u = 0; u < 4; ++u) {
                const float4 qv = *(const float4*)&Qs[ii4 * 4 + u][tx * 4];
                #pragma unroll
                for (int i = 0; i < 4; ++i) {
                    const float pw = (u == 0) ? pv[i].x : (u == 1) ? pv[i].y
                                   : (u == 2) ? pv[i].z : pv[i].w;
                    acc[i][0] += pw * qv.x; acc[i][1] += pw * qv.y;
                    acc[i][2] += pw * qv.z; acc[i][3] += pw * qv.w;
                }
            }
        }
    }
    float* dkbase = dqk + (size_t)b * 512 * C2 + DDIM + h * HDIM;
    #pragma unroll
    for (int i = 0; i < 4; ++i) {
        const float4 v = make_float4(acc[i][0], acc[i][1], acc[i][2], acc[i][3]);
        *(float4*)&dkbase[(size_t)(jt + ty * 4 + i) * C2 + tx * 4] = v;
    }
}

// ---------------------------------------------------------------------------
// LN backward + gradient step.  G = -(dE/dg) accumulated; update is
// x_new = x + ALPHA * rstd * (gamma*G - mean(gamma*G) - xhat*mean(gamma*G*xhat))
// ---------------------------------------------------------------------------
__global__ __launch_bounds__(256) void ln_bwd_update(const float* __restrict__ G,
                                                     const float* __restrict__ xhat,
                                                     const float* __restrict__ rstd,
                                                     const float* __restrict__ gamma,
                                                     const float* __restrict__ xin,
                                                     float* __restrict__ xout) {
    const int row = blockIdx.x;
    const int tid = threadIdx.x;
    const float* Gr = G    + (size_t)row * DDIM;
    const float* xh = xhat + (size_t)row * DDIM;
    float dxh[3], xhv[3];
    float s1 = 0.f, s2 = 0.f;
    #pragma unroll
    for (int c = 0; c < 3; ++c) {
        const int d = tid + c * 256;
        dxh[c] = gamma[d] * Gr[d];
        xhv[c] = xh[d];
        s1 += dxh[c];
        s2 += dxh[c] * xhv[c];
    }
    __shared__ float sb1[4], sb2[4];
    for (int off = 32; off > 0; off >>= 1) {
        s1 += __shfl_down(s1, off, 64);
        s2 += __shfl_down(s2, off, 64);
    }
    const int lane = tid & 63, wid = tid >> 6;
    if (lane == 0) { sb1[wid] = s1; sb2[wid] = s2; }
    __syncthreads();
    s1 = sb1[0] + sb1[1] + sb1[2] + sb1[3];
    s2 = sb2[0] + sb2[1] + sb2[2] + sb2[3];
    const float rs = rstd[row];
    const float m1 = s1 * (1.0f / DDIM);
    const float m2 = s2 * (1.0f / DDIM);
    #pragma unroll
    for (int c = 0; c < 3; ++c) {
        const int d = tid + c * 256;
        const float dx = rs * (dxh[c] - m1 - xhv[c] * m2);
        xout[(size_t)row * DDIM + d] = xin[(size_t)row * DDIM + d] + ALPHA * dx;
    }
}

// ---------------------------------------------------------------------------
extern "C" void kernel_launch(void* const* d_in, const int* in_sizes, int n_in,
                              void* d_out, int out_size, void* d_ws, size_t ws_size,
                              hipStream_t stream) {
    (void)in_sizes; (void)n_in; (void)out_size; (void)ws_size;
    const float* x     = (const float*)d_in[0];
    const float* gamma = (const float*)d_in[1];
    const float* delta = (const float*)d_in[2];
    const float* Wq    = (const float*)d_in[3];
    const float* Wk    = (const float*)d_in[4];
    const float* xi    = (const float*)d_in[5];
    float* out = (float*)d_out;
    float* ws  = (float*)d_ws;

    // workspace layout (floats) — total ~17.33M floats = 69.3 MB
    float* g    = ws;                    // 2048*768
    float* xhat = g    + (size_t)NTOK * DDIM;
    float* dg   = xhat + (size_t)NTOK * DDIM;
    float* qk   = dg   + (size_t)NTOK * DDIM;   // 2048*1536 (q||k)
    float* dqk  = qk   + (size_t)NTOK * C2;     // 2048*1536 (dq||dk, positive)
    float* R    = dqk  + (size_t)NTOK * C2;     // 2048*3072 relu(g xi^T)
    float* rstd = R    + (size_t)NTOK * MMEM;   // 2048
    float* lse  = rstd + NTOK;                  // B*H*N = 24576

    for (int s = 0; s < NSTEPS; ++s) {
        const float* xs = (s == 0) ? x : out;
        ln_fwd<<<dim3(NTOK), dim3(256), 0, stream>>>(xs, gamma, delta, g, xhat, rstd);
        // Hopfield: R = relu(g xi^T); dg = R @ xi
        gemm_k<2, true,  false><<<dim3(MMEM / 64, NTOK / 64), dim3(256), 0, stream>>>(
            g, xi, nullptr, R, NTOK, MMEM, DDIM);
        gemm_k<0, false, false><<<dim3(DDIM / 64, NTOK / 64), dim3(256), 0, stream>>>(
            R, xi, nullptr, dg, NTOK, DDIM, MMEM);
        // Attention: qk proj, flash dq/dk, pullback (accumulate into dg)
        gemm_k<1, false, false><<<dim3(C2 / 64, NTOK / 64), dim3(256), 0, stream>>>(
            g, Wq, Wk, qk, NTOK, C2, DDIM);
        attn_dq<<<dim3(8, NHEAD, 4), dim3(256), 0, stream>>>(qk, dqk, lse);
        attn_dk<<<dim3(8, NHEAD, 4), dim3(256), 0, stream>>>(qk, dqk, lse);
        gemm_k<3, false, true><<<dim3(DDIM / 64, NTOK / 64), dim3(256), 0, stream>>>(
            dqk, Wq, Wk, dg, NTOK, DDIM, C2);
        // LN backward + step
        ln_bwd_update<<<dim3(NTOK), dim3(256), 0, stream>>>(
            dg, xhat, rstd, gamma, xs, out);
    }
}

// Round 12
// 4349.223 us; speedup vs baseline: 1.9040x; 1.9040x over previous
//
#include <hip/hip_runtime.h>
#include <math.h>

// (B,N,D,H,HD,M) = (4,512,768,12,64,3072)
#define NTOK   2048
#define DDIM   768
#define NHEAD  12
#define HDIM   64
#define MMEM   3072
#define C2     1536
#define NSTEPS 12
#define ALPHA  0.125f
#define BETA   0.125f
#define LNEPS  1e-5f

typedef unsigned short u16;
typedef __attribute__((ext_vector_type(8))) __bf16 bf16x8;
typedef __attribute__((ext_vector_type(4))) float  f32x4;

__device__ __forceinline__ u16 f2bf(float f) {
    unsigned int u = __float_as_uint(f);
    return (u16)((u + 0x7fffu + ((u >> 16) & 1u)) >> 16);
}

// ---------------------------------------------------------------------------
// One-time prep: xi fp32 [3072][768] -> xib bf16 [3072][768] + xibT bf16
// [768][3072].  64x64 tiled transpose through LDS.
// ---------------------------------------------------------------------------
__global__ __launch_bounds__(256) void conv_xi(const float* __restrict__ xi,
                                               u16* __restrict__ xib,
                                               u16* __restrict__ xibT) {
    __shared__ float T[64][65];
    const int t = threadIdx.x;
    const int c0 = blockIdx.x * 64;   // col tile (768/64 = 12)
    const int r0 = blockIdx.y * 64;   // row tile (3072/64 = 48)
    const int col = t & 63;
    #pragma unroll
    for (int it = 0; it < 16; ++it) {
        const int ro = (t >> 6) + it * 4;
        const float v = xi[(size_t)(r0 + ro) * DDIM + c0 + col];
        xib[(size_t)(r0 + ro) * DDIM + c0 + col] = f2bf(v);
        T[ro][col] = v;
    }
    __syncthreads();
    const int dd = t & 63;
    #pragma unroll
    for (int it = 0; it < 16; ++it) {
        const int e = (t >> 6) + it * 4;
        xibT[(size_t)(c0 + e) * MMEM + r0 + dd] = f2bf(T[dd][e]);
    }
}

// ---------------------------------------------------------------------------
// One-time prep: Pb bf16 [768][1536], Pb[d][n] = W{q|k}[h][d][e] (n=h*64+e).
// ---------------------------------------------------------------------------
__global__ __launch_bounds__(256) void conv_p(const float* __restrict__ Wq,
                                              const float* __restrict__ Wk,
                                              u16* __restrict__ Pb) {
    const int d = blockIdx.x;
    const int n = blockIdx.y * 256 + threadIdx.x;
    const float* W = (n < DDIM) ? Wq : Wk;
    const int n2 = (n < DDIM) ? n : n - DDIM;
    const int h = n2 >> 6, e = n2 & 63;
    Pb[(size_t)d * C2 + n] = f2bf(W[(size_t)h * (DDIM * HDIM) + (size_t)d * HDIM + e]);
}

// ---------------------------------------------------------------------------
// One-time prep: PTb bf16 [1536][768], PTb[n][d] = W{q|k}[h][d][e].
// Per block: transpose one [64d x 64e] tile of one head-half.
// ---------------------------------------------------------------------------
__global__ __launch_bounds__(256) void conv_pT(const float* __restrict__ Wq,
                                               const float* __restrict__ Wk,
                                               u16* __restrict__ PTb) {
    __shared__ float T[64][65];
    const int t = threadIdx.x;
    const int d0 = blockIdx.x * 64;   // 12 tiles over DDIM
    const int hb = blockIdx.y;        // 24 head-halves
    const float* W = (hb < NHEAD) ? Wq : Wk;
    const int h = (hb < NHEAD) ? hb : hb - NHEAD;
    const int col = t & 63;           // e
    #pragma unroll
    for (int it = 0; it < 16; ++it) {
        const int ro = (t >> 6) + it * 4;   // d offset
        T[ro][col] = W[(size_t)h * (DDIM * HDIM) + (size_t)(d0 + ro) * HDIM + col];
    }
    __syncthreads();
    const int dd = t & 63;            // d offset on write
    #pragma unroll
    for (int it = 0; it < 16; ++it) {
        const int e = (t >> 6) + it * 4;
        PTb[(size_t)(hb * 64 + e) * DDIM + d0 + dd] = f2bf(T[dd][e]);
    }
}

// ---------------------------------------------------------------------------
// LayerNorm forward: x -> gb (bf16), xhat (fp32), rstd.
// ---------------------------------------------------------------------------
__global__ __launch_bounds__(256) void ln_fwd(const float* __restrict__ x,
                                              const float* __restrict__ gamma,
                                              const float* __restrict__ delta,
                                              u16* __restrict__ gb,
                                              float* __restrict__ xhat,
                                              float* __restrict__ rstd) {
    const int row = blockIdx.x;
    const int tid = threadIdx.x;
    const float* xr = x + (size_t)row * DDIM;
    float v[3];
    v[0] = xr[tid]; v[1] = xr[tid + 256]; v[2] = xr[tid + 512];
    float s1 = v[0] + v[1] + v[2];
    float s2 = v[0]*v[0] + v[1]*v[1] + v[2]*v[2];
    __shared__ float sb1[4], sb2[4];
    for (int off = 32; off > 0; off >>= 1) {
        s1 += __shfl_down(s1, off, 64);
        s2 += __shfl_down(s2, off, 64);
    }
    const int lane = tid & 63, wid = tid >> 6;
    if (lane == 0) { sb1[wid] = s1; sb2[wid] = s2; }
    __syncthreads();
    s1 = sb1[0] + sb1[1] + sb1[2] + sb1[3];
    s2 = sb2[0] + sb2[1] + sb2[2] + sb2[3];
    const float mu  = s1 * (1.0f / DDIM);
    const float var = s2 * (1.0f / DDIM) - mu * mu;
    const float rs  = 1.0f / sqrtf(var + LNEPS);
    if (tid == 0) rstd[row] = rs;
    #pragma unroll
    for (int c = 0; c < 3; ++c) {
        const int d = tid + c * 256;
        const float xh = (v[c] - mu) * rs;
        xhat[(size_t)row * DDIM + d] = xh;
        gb[(size_t)row * DDIM + d]  = f2bf(gamma[d] * xh + delta[d]);
    }
}

// ---------------------------------------------------------------------------
// bf16 MFMA GEMM: C[m,n] = sum_k A[m,k] * Bt[n,k]   (both bf16 row-major)
// 128x128 tile, 4 waves (2x2), each wave 64x64 = 4x4 frags of 16x16x32.
// OUT 0: Cb = bf16(relu(acc));  OUT 1: Cf = acc;  OUT 2: Cf += acc.
// LDS pitch 56 (112B): 16B-aligned b128 ops, ~2-way bank aliasing (free).
// ---------------------------------------------------------------------------
template<int OUT>
__global__ __launch_bounds__(256) void gemm_bf(const u16* __restrict__ A,
                                               const u16* __restrict__ Bt,
                                               float* __restrict__ Cf,
                                               u16* __restrict__ Cb,
                                               int K, int ldc) {
    __shared__ __attribute__((aligned(16))) u16 As[128 * 56];
    __shared__ __attribute__((aligned(16))) u16 Bs[128 * 56];
    const int tid = threadIdx.x;
    const int bm = blockIdx.y * 128, bn = blockIdx.x * 128;
    const int lane = tid & 63, w = tid >> 6, wm = w >> 1, wn = w & 1;
    f32x4 acc[4][4];
    #pragma unroll
    for (int i = 0; i < 4; ++i)
        #pragma unroll
        for (int j = 0; j < 4; ++j)
            acc[i][j] = (f32x4){0.f, 0.f, 0.f, 0.f};

    const int rb = ((lane & 15) * 56) + ((lane >> 4) << 3);
    for (int k0 = 0; k0 < K; k0 += 32) {
        #pragma unroll
        for (int p = 0; p < 2; ++p) {
            const int lin = p * 256 + tid;
            const int row = lin >> 2;
            const int seg = (lin & 3) << 3;
            *(uint4*)&As[row * 56 + seg] =
                *(const uint4*)&A[(size_t)(bm + row) * K + k0 + seg];
            *(uint4*)&Bs[row * 56 + seg] =
                *(const uint4*)&Bt[(size_t)(bn + row) * K + k0 + seg];
        }
        __syncthreads();
        bf16x8 af[4], bfv[4];
        #pragma unroll
        for (int mi = 0; mi < 4; ++mi)
            af[mi] = *(const bf16x8*)&As[(wm * 64 + mi * 16) * 56 + rb];
        #pragma unroll
        for (int nj = 0; nj < 4; ++nj)
            bfv[nj] = *(const bf16x8*)&Bs[(wn * 64 + nj * 16) * 56 + rb];
        #pragma unroll
        for (int mi = 0; mi < 4; ++mi)
            #pragma unroll
            for (int nj = 0; nj < 4; ++nj)
                acc[mi][nj] = __builtin_amdgcn_mfma_f32_16x16x32_bf16(
                    af[mi], bfv[nj], acc[mi][nj], 0, 0, 0);
        __syncthreads();
    }
    // C/D layout: col = lane&15, row = (lane>>4)*4 + reg   [m89/m91]
    const int rr = (lane >> 4) << 2;
    const int cc = lane & 15;
    #pragma unroll
    for (int mi = 0; mi < 4; ++mi)
        #pragma unroll
        for (int nj = 0; nj < 4; ++nj) {
            const int grow0 = bm + wm * 64 + mi * 16 + rr;
            const int gcol  = bn + wn * 64 + nj * 16 + cc;
            #pragma unroll
            for (int r = 0; r < 4; ++r) {
                const float v = acc[mi][nj][r];
                const size_t off = (size_t)(grow0 + r) * ldc + gcol;
                if (OUT == 0) Cb[off] = f2bf(fmaxf(v, 0.f));
                if (OUT == 1) Cf[off] = v;
                if (OUT == 2) Cf[off] += v;
            }
        }
}

// ---------------------------------------------------------------------------
// Attention pass A (fp32): online softmax over keys; writes dqkb (bf16) + lse.
// dq_store[i,:] = softmax_j(beta q_i.k_j) @ K  (positive; true grad = -this)
// ---------------------------------------------------------------------------
__global__ __launch_bounds__(256) void attn_dq(const float* __restrict__ qk,
                                               u16* __restrict__ dqkb,
                                               float* __restrict__ lse) {
    __shared__ __attribute__((aligned(16))) float Qs[64][68];
    __shared__ __attribute__((aligned(16))) float Ks[64][68];
    __shared__ __attribute__((aligned(16))) float Ps[64][68];
    const int tid = threadIdx.x;
    const int tx = tid & 15, ty = tid >> 4;
    const int it = blockIdx.x * 64;
    const int h = blockIdx.y, b = blockIdx.z;
    const float* qbase = qk + (size_t)b * 512 * C2 + h * HDIM;
    const float* kbase = qbase + DDIM;
    #pragma unroll 4
    for (int p = 0; p < 16; ++p) {
        const int r = (tid >> 6) + p * 4, e = tid & 63;
        Qs[r][e] = qbase[(size_t)(it + r) * C2 + e];
    }
    float m[4], l[4], acc[4][4];
    #pragma unroll
    for (int i = 0; i < 4; ++i) {
        m[i] = -1e30f; l[i] = 0.f;
        #pragma unroll
        for (int j = 0; j < 4; ++j) acc[i][j] = 0.f;
    }
    for (int jt = 0; jt < 512; jt += 64) {
        __syncthreads();
        #pragma unroll 4
        for (int p = 0; p < 16; ++p) {
            const int r = (tid >> 6) + p * 4, e = tid & 63;
            Ks[r][e] = kbase[(size_t)(jt + r) * C2 + e];
        }
        __syncthreads();
        float s[4][4];
        #pragma unroll
        for (int i = 0; i < 4; ++i)
            #pragma unroll
            for (int j = 0; j < 4; ++j) s[i][j] = 0.f;
        #pragma unroll 4
        for (int e4 = 0; e4 < 16; ++e4) {
            float4 a[4], bb[4];
            #pragma unroll
            for (int i = 0; i < 4; ++i) a[i]  = *(const float4*)&Qs[ty * 4 + i][e4 * 4];
            #pragma unroll
            for (int j = 0; j < 4; ++j) bb[j] = *(const float4*)&Ks[tx * 4 + j][e4 * 4];
            #pragma unroll
            for (int i = 0; i < 4; ++i)
                #pragma unroll
                for (int j = 0; j < 4; ++j)
                    s[i][j] += a[i].x * bb[j].x + a[i].y * bb[j].y
                             + a[i].z * bb[j].z + a[i].w * bb[j].w;
        }
        #pragma unroll
        for (int i = 0; i < 4; ++i) {
            float rmax = -1e30f;
            #pragma unroll
            for (int j = 0; j < 4; ++j) { s[i][j] *= BETA; rmax = fmaxf(rmax, s[i][j]); }
            #pragma unroll
            for (int off = 1; off < 16; off <<= 1) rmax = fmaxf(rmax, __shfl_xor(rmax, off, 16));
            const float mnew = fmaxf(m[i], rmax);
            const float sc = expf(m[i] - mnew);
            float rsum = 0.f;
            #pragma unroll
            for (int j = 0; j < 4; ++j) { s[i][j] = expf(s[i][j] - mnew); rsum += s[i][j]; }
            #pragma unroll
            for (int off = 1; off < 16; off <<= 1) rsum += __shfl_xor(rsum, off, 16);
            l[i] = l[i] * sc + rsum;
            m[i] = mnew;
            #pragma unroll
            for (int j = 0; j < 4; ++j) acc[i][j] *= sc;
            #pragma unroll
            for (int j = 0; j < 4; ++j) Ps[ty * 4 + i][tx * 4 + j] = s[i][j];
        }
        __syncthreads();
        #pragma unroll 4
        for (int jj4 = 0; jj4 < 16; ++jj4) {
            float4 pv[4];
            #pragma unroll
            for (int i = 0; i < 4; ++i) pv[i] = *(const float4*)&Ps[ty * 4 + i][jj4 * 4];
            #pragma unroll
            for (int u = 0; u < 4; ++u) {
                const float4 kv = *(const float4*)&Ks[jj4 * 4 + u][tx * 4];
                #pragma unroll
                for (int i = 0; i < 4; ++i) {
                    const float pw = (u == 0) ? pv[i].x : (u == 1) ? pv[i].y
                                   : (u == 2) ? pv[i].z : pv[i].w;
                    acc[i][0] += pw * kv.x; acc[i][1] += pw * kv.y;
                    acc[i][2] += pw * kv.z; acc[i][3] += pw * kv.w;
                }
            }
        }
    }
    u16* dqb = dqkb + (size_t)b * 512 * C2 + h * HDIM;
    #pragma unroll
    for (int i = 0; i < 4; ++i) {
        const float inv = 1.0f / l[i];
        ushort4 o;
        o.x = f2bf(acc[i][0] * inv); o.y = f2bf(acc[i][1] * inv);
        o.z = f2bf(acc[i][2] * inv); o.w = f2bf(acc[i][3] * inv);
        *(ushort4*)&dqb[(size_t)(it + ty * 4 + i) * C2 + tx * 4] = o;
        if (tx == 0)
            lse[(size_t)(b * NHEAD + h) * 512 + it + ty * 4 + i] = m[i] + logf(l[i]);
    }
}

// ---------------------------------------------------------------------------
// Attention pass B (fp32): dk_store[j,:] = sum_i p_ij q_i -> dqkb k-half.
// ---------------------------------------------------------------------------
__global__ __launch_bounds__(256) void attn_dk(const float* __restrict__ qk,
                                               u16* __restrict__ dqkb,
                                               const float* __restrict__ lse) {
    __shared__ __attribute__((aligned(16))) float Ks[64][68];
    __shared__ __attribute__((aligned(16))) float Qs[64][68];
    __shared__ __attribute__((aligned(16))) float Ps[64][68];
    __shared__ float Ls[64];
    const int tid = threadIdx.x;
    const int tx = tid & 15, ty = tid >> 4;
    const int jt = blockIdx.x * 64;
    const int h = blockIdx.y, b = blockIdx.z;
    const float* qbase = qk + (size_t)b * 512 * C2 + h * HDIM;
    const float* kbase = qbase + DDIM;
    #pragma unroll 4
    for (int p = 0; p < 16; ++p) {
        const int r = (tid >> 6) + p * 4, e = tid & 63;
        Ks[r][e] = kbase[(size_t)(jt + r) * C2 + e];
    }
    float acc[4][4];
    #pragma unroll
    for (int i = 0; i < 4; ++i)
        #pragma unroll
        for (int j = 0; j < 4; ++j) acc[i][j] = 0.f;
    for (int it = 0; it < 512; it += 64) {
        __syncthreads();
        #pragma unroll 4
        for (int p = 0; p < 16; ++p) {
            const int r = (tid >> 6) + p * 4, e = tid & 63;
            Qs[r][e] = qbase[(size_t)(it + r) * C2 + e];
        }
        if (tid < 64) Ls[tid] = lse[(size_t)(b * NHEAD + h) * 512 + it + tid];
        __syncthreads();
        float s[4][4];
        #pragma unroll
        for (int i = 0; i < 4; ++i)
            #pragma unroll
            for (int j = 0; j < 4; ++j) s[i][j] = 0.f;
        #pragma unroll 4
        for (int e4 = 0; e4 < 16; ++e4) {
            float4 a[4], bb[4];
            #pragma unroll
            for (int i = 0; i < 4; ++i) a[i]  = *(const float4*)&Ks[ty * 4 + i][e4 * 4];
            #pragma unroll
            for (int j = 0; j < 4; ++j) bb[j] = *(const float4*)&Qs[tx * 4 + j][e4 * 4];
            #pragma unroll
            for (int i = 0; i < 4; ++i)
                #pragma unroll
                for (int j = 0; j < 4; ++j)
                    s[i][j] += a[i].x * bb[j].x + a[i].y * bb[j].y
                             + a[i].z * bb[j].z + a[i].w * bb[j].w;
        }
        #pragma unroll
        for (int i = 0; i < 4; ++i)
            #pragma unroll
            for (int j = 0; j < 4; ++j)
                Ps[ty * 4 + i][tx * 4 + j] = expf(s[i][j] * BETA - Ls[tx * 4 + j]);
        __syncthreads();
        #pragma unroll 4
        for (int ii4 = 0; ii4 < 16; ++ii4) {
            float4 pv[4];
            #pragma unroll
            for (int i = 0; i < 4; ++i) pv[i] = *(const float4*)&Ps[ty * 4 + i][ii4 * 4];
            #pragma unroll
            for (int u = 0; u < 4; ++u) {
                const float4 qv = *(const float4*)&Qs[ii4 * 4 + u][tx * 4];
                #pragma unroll
                for (int i = 0; i < 4; ++i) {
                    const float pw = (u == 0) ? pv[i].x : (u == 1) ? pv[i].y
                                   : (u == 2) ? pv[i].z : pv[i].w;
                    acc[i][0] += pw * qv.x; acc[i][1] += pw * qv.y;
                    acc[i][2] += pw * qv.z; acc[i][3] += pw * qv.w;
                }
            }
        }
    }
    u16* dkb = dqkb + (size_t)b * 512 * C2 + DDIM + h * HDIM;
    #pragma unroll
    for (int i = 0; i < 4; ++i) {
        ushort4 o;
        o.x = f2bf(acc[i][0]); o.y = f2bf(acc[i][1]);
        o.z = f2bf(acc[i][2]); o.w = f2bf(acc[i][3]);
        *(ushort4*)&dkb[(size_t)(jt + ty * 4 + i) * C2 + tx * 4] = o;
    }
}

// ---------------------------------------------------------------------------
// LN backward + gradient step (fp32).  G = -(dE/dg);
// x_new = x + ALPHA * rstd * (gam*G - mean(gam*G) - xhat*mean(gam*G*xhat))
// ---------------------------------------------------------------------------
__global__ __launch_bounds__(256) void ln_bwd_update(const float* __restrict__ G,
                                                     const float* __restrict__ xhat,
                                                     const float* __restrict__ rstd,
                                                     const float* __restrict__ gamma,
                                                     const float* __restrict__ xin,
                                                     float* __restrict__ xout) {
    const int row = blockIdx.x;
    const int tid = threadIdx.x;
    const float* Gr = G    + (size_t)row * DDIM;
    const float* xh = xhat + (size_t)row * DDIM;
    float dxh[3], xhv[3];
    float s1 = 0.f, s2 = 0.f;
    #pragma unroll
    for (int c = 0; c < 3; ++c) {
        const int d = tid + c * 256;
        dxh[c] = gamma[d] * Gr[d];
        xhv[c] = xh[d];
        s1 += dxh[c];
        s2 += dxh[c] * xhv[c];
    }
    __shared__ float sb1[4], sb2[4];
    for (int off = 32; off > 0; off >>= 1) {
        s1 += __shfl_down(s1, off, 64);
        s2 += __shfl_down(s2, off, 64);
    }
    const int lane = tid & 63, wid = tid >> 6;
    if (lane == 0) { sb1[wid] = s1; sb2[wid] = s2; }
    __syncthreads();
    s1 = sb1[0] + sb1[1] + sb1[2] + sb1[3];
    s2 = sb2[0] + sb2[1] + sb2[2] + sb2[3];
    const float rs = rstd[row];
    const float m1 = s1 * (1.0f / DDIM);
    const float m2 = s2 * (1.0f / DDIM);
    #pragma unroll
    for (int c = 0; c < 3; ++c) {
        const int d = tid + c * 256;
        const float dx = rs * (dxh[c] - m1 - xhv[c] * m2);
        xout[(size_t)row * DDIM + d] = xin[(size_t)row * DDIM + d] + ALPHA * dx;
    }
}

// ---------------------------------------------------------------------------
extern "C" void kernel_launch(void* const* d_in, const int* in_sizes, int n_in,
                              void* d_out, int out_size, void* d_ws, size_t ws_size,
                              hipStream_t stream) {
    (void)in_sizes; (void)n_in; (void)out_size; (void)ws_size;
    const float* x     = (const float*)d_in[0];
    const float* gamma = (const float*)d_in[1];
    const float* delta = (const float*)d_in[2];
    const float* Wq    = (const float*)d_in[3];
    const float* Wk    = (const float*)d_in[4];
    const float* xi    = (const float*)d_in[5];
    float* out = (float*)d_out;

    // workspace layout (~62 MB)
    char* p = (char*)d_ws;
    u16* gb   = (u16*)p;  p += (size_t)NTOK * DDIM * 2;   // bf16 g
    u16* Rb   = (u16*)p;  p += (size_t)NTOK * MMEM * 2;   // bf16 relu(g xi^T)
    u16* dqkb = (u16*)p;  p += (size_t)NTOK * C2   * 2;   // bf16 dq||dk
    u16* xib  = (u16*)p;  p += (size_t)MMEM * DDIM * 2;   // bf16 xi
    u16* xibT = (u16*)p;  p += (size_t)DDIM * MMEM * 2;   // bf16 xi^T
    u16* Pb   = (u16*)p;  p += (size_t)DDIM * C2   * 2;   // bf16 P  [768][1536]
    u16* PTb  = (u16*)p;  p += (size_t)C2   * DDIM * 2;   // bf16 P^T[1536][768]
    float* xhat = (float*)p; p += (size_t)NTOK * DDIM * 4;
    float* dg   = (float*)p; p += (size_t)NTOK * DDIM * 4;
    float* qk   = (float*)p; p += (size_t)NTOK * C2   * 4;
    float* rstd = (float*)p; p += (size_t)NTOK * 4;
    float* lse  = (float*)p;

    // one-time operand prep (repeated every launch for graph-capture safety)
    conv_xi<<<dim3(12, 48), dim3(256), 0, stream>>>(xi, xib, xibT);
    conv_p <<<dim3(DDIM, 6), dim3(256), 0, stream>>>(Wq, Wk, Pb);
    conv_pT<<<dim3(12, 24), dim3(256), 0, stream>>>(Wq, Wk, PTb);

    for (int s = 0; s < NSTEPS; ++s) {
        const float* xs = (s == 0) ? x : out;
        ln_fwd<<<dim3(NTOK), dim3(256), 0, stream>>>(xs, gamma, delta, gb, xhat, rstd);
        // Hopfield: Rb = bf16(relu(gb xi^T)); dg = Rb @ xi
        gemm_bf<0><<<dim3(MMEM / 128, NTOK / 128), dim3(256), 0, stream>>>(
            gb, xib, nullptr, Rb, DDIM, MMEM);
        gemm_bf<1><<<dim3(DDIM / 128, NTOK / 128), dim3(256), 0, stream>>>(
            Rb, xibT, dg, nullptr, MMEM, DDIM);
        // Attention: qk = gb @ P, flash dq/dk, dg += dqkb @ P^T
        gemm_bf<1><<<dim3(C2 / 128, NTOK / 128), dim3(256), 0, stream>>>(
            gb, PTb, qk, nullptr, DDIM, C2);
        attn_dq<<<dim3(8, NHEAD, 4), dim3(256), 0, stream>>>(qk, dqkb, lse);
        attn_dk<<<dim3(8, NHEAD, 4), dim3(256), 0, stream>>>(qk, dqkb, lse);
        gemm_bf<2><<<dim3(DDIM / 128, NTOK / 128), dim3(256), 0, stream>>>(
            dqkb, Pb, dg, nullptr, C2, DDIM);
        // LN backward + step
        ln_bwd_update<<<dim3(NTOK), dim3(256), 0, stream>>>(
            dg, xhat, rstd, gamma, xs, out);
    }
}

// Round 13
// 2869.286 us; speedup vs baseline: 2.8860x; 1.5158x over previous
//
#include <hip/hip_runtime.h>
#include <math.h>

// (B,N,D,H,HD,M) = (4,512,768,12,64,3072)
#define NTOK   2048
#define DDIM   768
#define NHEAD  12
#define HDIM   64
#define MMEM   3072
#define C2     1536
#define NSTEPS 12
#define ALPHA  0.125f
#define BETA   0.125f
#define LNEPS  1e-5f
#define PITCH  72    // bf16 LDS pitch for attention tiles (144B, 16B-aligned)

typedef unsigned short u16;
typedef __attribute__((ext_vector_type(8))) __bf16 bf16x8;
typedef __attribute__((ext_vector_type(4))) float  f32x4;

__device__ __forceinline__ u16 f2bf(float f) {
    unsigned int u = __float_as_uint(f);
    return (u16)((u + 0x7fffu + ((u >> 16) & 1u)) >> 16);
}

// ---------------------------------------------------------------------------
// One-time prep: xi fp32 [3072][768] -> xib bf16 + xibT bf16 [768][3072].
// ---------------------------------------------------------------------------
__global__ __launch_bounds__(256) void conv_xi(const float* __restrict__ xi,
                                               u16* __restrict__ xib,
                                               u16* __restrict__ xibT) {
    __shared__ float T[64][65];
    const int t = threadIdx.x;
    const int c0 = blockIdx.x * 64;
    const int r0 = blockIdx.y * 64;
    const int col = t & 63;
    #pragma unroll
    for (int it = 0; it < 16; ++it) {
        const int ro = (t >> 6) + it * 4;
        const float v = xi[(size_t)(r0 + ro) * DDIM + c0 + col];
        xib[(size_t)(r0 + ro) * DDIM + c0 + col] = f2bf(v);
        T[ro][col] = v;
    }
    __syncthreads();
    const int dd = t & 63;
    #pragma unroll
    for (int it = 0; it < 16; ++it) {
        const int e = (t >> 6) + it * 4;
        xibT[(size_t)(c0 + e) * MMEM + r0 + dd] = f2bf(T[dd][e]);
    }
}

// ---------------------------------------------------------------------------
// One-time prep: Pb bf16 [768][1536], Pb[d][n] = W{q|k}[h][d][e] (n=h*64+e).
// ---------------------------------------------------------------------------
__global__ __launch_bounds__(256) void conv_p(const float* __restrict__ Wq,
                                              const float* __restrict__ Wk,
                                              u16* __restrict__ Pb) {
    const int d = blockIdx.x;
    const int n = blockIdx.y * 256 + threadIdx.x;
    const float* W = (n < DDIM) ? Wq : Wk;
    const int n2 = (n < DDIM) ? n : n - DDIM;
    const int h = n2 >> 6, e = n2 & 63;
    Pb[(size_t)d * C2 + n] = f2bf(W[(size_t)h * (DDIM * HDIM) + (size_t)d * HDIM + e]);
}

// ---------------------------------------------------------------------------
// One-time prep: PTb bf16 [1536][768], PTb[n][d] = W{q|k}[h][d][e].
// ---------------------------------------------------------------------------
__global__ __launch_bounds__(256) void conv_pT(const float* __restrict__ Wq,
                                               const float* __restrict__ Wk,
                                               u16* __restrict__ PTb) {
    __shared__ float T[64][65];
    const int t = threadIdx.x;
    const int d0 = blockIdx.x * 64;
    const int hb = blockIdx.y;
    const float* W = (hb < NHEAD) ? Wq : Wk;
    const int h = (hb < NHEAD) ? hb : hb - NHEAD;
    const int col = t & 63;
    #pragma unroll
    for (int it = 0; it < 16; ++it) {
        const int ro = (t >> 6) + it * 4;
        T[ro][col] = W[(size_t)h * (DDIM * HDIM) + (size_t)(d0 + ro) * HDIM + col];
    }
    __syncthreads();
    const int dd = t & 63;
    #pragma unroll
    for (int it = 0; it < 16; ++it) {
        const int e = (t >> 6) + it * 4;
        PTb[(size_t)(hb * 64 + e) * DDIM + d0 + dd] = f2bf(T[dd][e]);
    }
}

// ---------------------------------------------------------------------------
// LayerNorm forward: x -> gb (bf16), xhat (fp32), rstd.
// ---------------------------------------------------------------------------
__global__ __launch_bounds__(256) void ln_fwd(const float* __restrict__ x,
                                              const float* __restrict__ gamma,
                                              const float* __restrict__ delta,
                                              u16* __restrict__ gb,
                                              float* __restrict__ xhat,
                                              float* __restrict__ rstd) {
    const int row = blockIdx.x;
    const int tid = threadIdx.x;
    const float* xr = x + (size_t)row * DDIM;
    float v[3];
    v[0] = xr[tid]; v[1] = xr[tid + 256]; v[2] = xr[tid + 512];
    float s1 = v[0] + v[1] + v[2];
    float s2 = v[0]*v[0] + v[1]*v[1] + v[2]*v[2];
    __shared__ float sb1[4], sb2[4];
    for (int off = 32; off > 0; off >>= 1) {
        s1 += __shfl_down(s1, off, 64);
        s2 += __shfl_down(s2, off, 64);
    }
    const int lane = tid & 63, wid = tid >> 6;
    if (lane == 0) { sb1[wid] = s1; sb2[wid] = s2; }
    __syncthreads();
    s1 = sb1[0] + sb1[1] + sb1[2] + sb1[3];
    s2 = sb2[0] + sb2[1] + sb2[2] + sb2[3];
    const float mu  = s1 * (1.0f / DDIM);
    const float var = s2 * (1.0f / DDIM) - mu * mu;
    const float rs  = 1.0f / sqrtf(var + LNEPS);
    if (tid == 0) rstd[row] = rs;
    #pragma unroll
    for (int c = 0; c < 3; ++c) {
        const int d = tid + c * 256;
        const float xh = (v[c] - mu) * rs;
        xhat[(size_t)row * DDIM + d] = xh;
        gb[(size_t)row * DDIM + d]  = f2bf(gamma[d] * xh + delta[d]);
    }
}

// ---------------------------------------------------------------------------
// bf16 MFMA GEMM: C[m,n] = sum_k A[m,k] * Bt[n,k]   (both bf16 row-major)
// 128x128 tile, 4 waves (2x2), each wave 64x64 = 4x4 frags of 16x16x32.
// OUT 0: Cb = bf16(relu(acc)); 1: Cf = acc; 2: Cf += acc; 3: Cb = bf16(acc).
// ---------------------------------------------------------------------------
template<int OUT>
__global__ __launch_bounds__(256) void gemm_bf(const u16* __restrict__ A,
                                               const u16* __restrict__ Bt,
                                               float* __restrict__ Cf,
                                               u16* __restrict__ Cb,
                                               int K, int ldc) {
    __shared__ __attribute__((aligned(16))) u16 As[128 * 56];
    __shared__ __attribute__((aligned(16))) u16 Bs[128 * 56];
    const int tid = threadIdx.x;
    const int bm = blockIdx.y * 128, bn = blockIdx.x * 128;
    const int lane = tid & 63, w = tid >> 6, wm = w >> 1, wn = w & 1;
    f32x4 acc[4][4];
    #pragma unroll
    for (int i = 0; i < 4; ++i)
        #pragma unroll
        for (int j = 0; j < 4; ++j)
            acc[i][j] = (f32x4){0.f, 0.f, 0.f, 0.f};

    const int rb = ((lane & 15) * 56) + ((lane >> 4) << 3);
    for (int k0 = 0; k0 < K; k0 += 32) {
        #pragma unroll
        for (int p = 0; p < 2; ++p) {
            const int lin = p * 256 + tid;
            const int row = lin >> 2;
            const int seg = (lin & 3) << 3;
            *(uint4*)&As[row * 56 + seg] =
                *(const uint4*)&A[(size_t)(bm + row) * K + k0 + seg];
            *(uint4*)&Bs[row * 56 + seg] =
                *(const uint4*)&Bt[(size_t)(bn + row) * K + k0 + seg];
        }
        __syncthreads();
        bf16x8 af[4], bfv[4];
        #pragma unroll
        for (int mi = 0; mi < 4; ++mi)
            af[mi] = *(const bf16x8*)&As[(wm * 64 + mi * 16) * 56 + rb];
        #pragma unroll
        for (int nj = 0; nj < 4; ++nj)
            bfv[nj] = *(const bf16x8*)&Bs[(wn * 64 + nj * 16) * 56 + rb];
        #pragma unroll
        for (int mi = 0; mi < 4; ++mi)
            #pragma unroll
            for (int nj = 0; nj < 4; ++nj)
                acc[mi][nj] = __builtin_amdgcn_mfma_f32_16x16x32_bf16(
                    af[mi], bfv[nj], acc[mi][nj], 0, 0, 0);
        __syncthreads();
    }
    const int rr = (lane >> 4) << 2;
    const int cc = lane & 15;
    #pragma unroll
    for (int mi = 0; mi < 4; ++mi)
        #pragma unroll
        for (int nj = 0; nj < 4; ++nj) {
            const int grow0 = bm + wm * 64 + mi * 16 + rr;
            const int gcol  = bn + wn * 64 + nj * 16 + cc;
            #pragma unroll
            for (int r = 0; r < 4; ++r) {
                const float v = acc[mi][nj][r];
                const size_t off = (size_t)(grow0 + r) * ldc + gcol;
                if (OUT == 0) Cb[off] = f2bf(fmaxf(v, 0.f));
                if (OUT == 1) Cf[off] = v;
                if (OUT == 2) Cf[off] += v;
                if (OUT == 3) Cb[off] = f2bf(v);
            }
        }
}

// ---------------------------------------------------------------------------
// MFMA attention pass A: per (64 q-rows, h, b); 4 waves x 16 rows.
// dq_store[i,:] = softmax_j(beta q_i.k_j) @ K   (positive); lse = m + log(l).
// Q,K bf16 in qkb layout [(b*512+n)*1536 + h*64 + e], k-half at +768.
// Fragment maps (16x16x32): A/B lane l -> row l&15, k-chunk (l>>4)*8.
// C/D lane l -> row (l>>4)*4+reg, col l&15.  [m89/m91]
// ---------------------------------------------------------------------------
__global__ __launch_bounds__(256) void attn_dq_mf(const u16* __restrict__ qkb,
                                                  u16* __restrict__ dqkb,
                                                  float* __restrict__ lse) {
    __shared__ __attribute__((aligned(16))) u16 Ks [64 * PITCH];
    __shared__ __attribute__((aligned(16))) u16 Kts[64 * PITCH];
    __shared__ __attribute__((aligned(16))) u16 Ps [64 * PITCH];
    const int tid = threadIdx.x;
    const int lane = tid & 63, wid = tid >> 6;
    const int it = blockIdx.x * 64, h = blockIdx.y, b = blockIdx.z;
    const u16* qbase = qkb + (size_t)b * 512 * C2 + h * HDIM;
    const u16* kbase = qbase + DDIM;
    const int l15 = lane & 15;
    const int ech = (lane >> 4) << 3;          // k-chunk offset 0/8/16/24
    // Q fragments in registers (wave's 16 rows)
    const int qrow = it + wid * 16 + l15;
    const bf16x8 qf0 = *(const bf16x8*)&qbase[(size_t)qrow * C2 + ech];
    const bf16x8 qf1 = *(const bf16x8*)&qbase[(size_t)qrow * C2 + ech + 32];
    float m[4], lsum[4];
    f32x4 oacc[4];
    #pragma unroll
    for (int r = 0; r < 4; ++r) { m[r] = -1e30f; lsum[r] = 0.f; }
    #pragma unroll
    for (int ne = 0; ne < 4; ++ne) oacc[ne] = (f32x4){0.f, 0.f, 0.f, 0.f};

    for (int jt = 0; jt < 512; jt += 64) {
        __syncthreads();
        #pragma unroll
        for (int p = 0; p < 4; ++p) {           // stage K row-major + transposed
            const int r = (tid >> 4) + p * 16;
            const int c = (tid & 15) * 4;
            const ushort4 v = *(const ushort4*)&kbase[(size_t)(jt + r) * C2 + c];
            *(ushort4*)&Ks[r * PITCH + c] = v;
            Kts[(c    ) * PITCH + r] = v.x;
            Kts[(c + 1) * PITCH + r] = v.y;
            Kts[(c + 2) * PITCH + r] = v.z;
            Kts[(c + 3) * PITCH + r] = v.w;
        }
        __syncthreads();
        // S = Q K^T : 16 rows x 64 cols per wave
        f32x4 sfr[4];
        #pragma unroll
        for (int nj = 0; nj < 4; ++nj) {
            const bf16x8 b0 = *(const bf16x8*)&Ks[(nj * 16 + l15) * PITCH + ech];
            const bf16x8 b1 = *(const bf16x8*)&Ks[(nj * 16 + l15) * PITCH + ech + 32];
            f32x4 s = (f32x4){0.f, 0.f, 0.f, 0.f};
            s = __builtin_amdgcn_mfma_f32_16x16x32_bf16(qf0, b0, s, 0, 0, 0);
            s = __builtin_amdgcn_mfma_f32_16x16x32_bf16(qf1, b1, s, 0, 0, 0);
            sfr[nj] = s;
        }
        // online softmax per row (row-reduce across 16-lane col groups)
        #pragma unroll
        for (int r = 0; r < 4; ++r) {
            float v0 = sfr[0][r] * BETA, v1 = sfr[1][r] * BETA;
            float v2 = sfr[2][r] * BETA, v3 = sfr[3][r] * BETA;
            float rmax = fmaxf(fmaxf(v0, v1), fmaxf(v2, v3));
            #pragma unroll
            for (int off = 1; off < 16; off <<= 1) rmax = fmaxf(rmax, __shfl_xor(rmax, off));
            const float mnew = fmaxf(m[r], rmax);
            const float sc = expf(m[r] - mnew);
            v0 = expf(v0 - mnew); v1 = expf(v1 - mnew);
            v2 = expf(v2 - mnew); v3 = expf(v3 - mnew);
            float rsum = v0 + v1 + v2 + v3;
            #pragma unroll
            for (int off = 1; off < 16; off <<= 1) rsum += __shfl_xor(rsum, off);
            lsum[r] = lsum[r] * sc + rsum;
            m[r] = mnew;
            #pragma unroll
            for (int ne = 0; ne < 4; ++ne) oacc[ne][r] *= sc;
            const int prow = wid * 16 + ((lane >> 4) << 2) + r;
            Ps[prow * PITCH +  0 + l15] = f2bf(v0);
            Ps[prow * PITCH + 16 + l15] = f2bf(v1);
            Ps[prow * PITCH + 32 + l15] = f2bf(v2);
            Ps[prow * PITCH + 48 + l15] = f2bf(v3);
        }
        // PV: O += P @ K  (A from own wave's Ps strip, B from Kt)
        const bf16x8 pa0 = *(const bf16x8*)&Ps[(wid * 16 + l15) * PITCH + ech];
        const bf16x8 pa1 = *(const bf16x8*)&Ps[(wid * 16 + l15) * PITCH + ech + 32];
        #pragma unroll
        for (int ne = 0; ne < 4; ++ne) {
            const bf16x8 kb0 = *(const bf16x8*)&Kts[(ne * 16 + l15) * PITCH + ech];
            const bf16x8 kb1 = *(const bf16x8*)&Kts[(ne * 16 + l15) * PITCH + ech + 32];
            oacc[ne] = __builtin_amdgcn_mfma_f32_16x16x32_bf16(pa0, kb0, oacc[ne], 0, 0, 0);
            oacc[ne] = __builtin_amdgcn_mfma_f32_16x16x32_bf16(pa1, kb1, oacc[ne], 0, 0, 0);
        }
    }
    u16* dqb = dqkb + (size_t)b * 512 * C2 + h * HDIM;
    #pragma unroll
    for (int r = 0; r < 4; ++r) {
        const int row = it + wid * 16 + ((lane >> 4) << 2) + r;
        const float inv = 1.0f / lsum[r];
        #pragma unroll
        for (int ne = 0; ne < 4; ++ne)
            dqb[(size_t)row * C2 + ne * 16 + l15] = f2bf(oacc[ne][r] * inv);
        if (l15 == 0)
            lse[(size_t)(b * NHEAD + h) * 512 + row] = m[r] + logf(lsum[r]);
    }
}

// ---------------------------------------------------------------------------
// MFMA attention pass B: dk_store[j,:] = sum_i p_ij q_i  (p from stored lse).
// Symmetric to pass A with Q<->K roles; no online state.
// ---------------------------------------------------------------------------
__global__ __launch_bounds__(256) void attn_dk_mf(const u16* __restrict__ qkb,
                                                  u16* __restrict__ dqkb,
                                                  const float* __restrict__ lse) {
    __shared__ __attribute__((aligned(16))) u16 Qs [64 * PITCH];
    __shared__ __attribute__((aligned(16))) u16 Qts[64 * PITCH];
    __shared__ __attribute__((aligned(16))) u16 Ps [64 * PITCH];
    __shared__ float Ls[64];
    const int tid = threadIdx.x;
    const int lane = tid & 63, wid = tid >> 6;
    const int jt = blockIdx.x * 64, h = blockIdx.y, b = blockIdx.z;
    const u16* qbase = qkb + (size_t)b * 512 * C2 + h * HDIM;
    const u16* kbase = qbase + DDIM;
    const int l15 = lane & 15;
    const int ech = (lane >> 4) << 3;
    const int krow = jt + wid * 16 + l15;
    const bf16x8 kf0 = *(const bf16x8*)&kbase[(size_t)krow * C2 + ech];
    const bf16x8 kf1 = *(const bf16x8*)&kbase[(size_t)krow * C2 + ech + 32];
    f32x4 oacc[4];
    #pragma unroll
    for (int ne = 0; ne < 4; ++ne) oacc[ne] = (f32x4){0.f, 0.f, 0.f, 0.f};

    for (int it = 0; it < 512; it += 64) {
        __syncthreads();
        #pragma unroll
        for (int p = 0; p < 4; ++p) {           // stage Q row-major + transposed
            const int r = (tid >> 4) + p * 16;
            const int c = (tid & 15) * 4;
            const ushort4 v = *(const ushort4*)&qbase[(size_t)(it + r) * C2 + c];
            *(ushort4*)&Qs[r * PITCH + c] = v;
            Qts[(c    ) * PITCH + r] = v.x;
            Qts[(c + 1) * PITCH + r] = v.y;
            Qts[(c + 2) * PITCH + r] = v.z;
            Qts[(c + 3) * PITCH + r] = v.w;
        }
        if (tid < 64) Ls[tid] = lse[(size_t)(b * NHEAD + h) * 512 + it + tid];
        __syncthreads();
        // S' = K Q^T : rows j, cols i
        #pragma unroll
        for (int ni = 0; ni < 4; ++ni) {
            const bf16x8 b0 = *(const bf16x8*)&Qs[(ni * 16 + l15) * PITCH + ech];
            const bf16x8 b1 = *(const bf16x8*)&Qs[(ni * 16 + l15) * PITCH + ech + 32];
            f32x4 s = (f32x4){0.f, 0.f, 0.f, 0.f};
            s = __builtin_amdgcn_mfma_f32_16x16x32_bf16(kf0, b0, s, 0, 0, 0);
            s = __builtin_amdgcn_mfma_f32_16x16x32_bf16(kf1, b1, s, 0, 0, 0);
            const float lv = Ls[ni * 16 + l15];   // lse for col i
            const int prow0 = wid * 16 + ((lane >> 4) << 2);
            #pragma unroll
            for (int r = 0; r < 4; ++r)
                Ps[(prow0 + r) * PITCH + ni * 16 + l15] = f2bf(expf(s[r] * BETA - lv));
        }
        // O += P' @ Q  (A from own wave's Ps strip, B from Qt)
        const bf16x8 pa0 = *(const bf16x8*)&Ps[(wid * 16 + l15) * PITCH + ech];
        const bf16x8 pa1 = *(const bf16x8*)&Ps[(wid * 16 + l15) * PITCH + ech + 32];
        #pragma unroll
        for (int ne = 0; ne < 4; ++ne) {
            const bf16x8 qb0 = *(const bf16x8*)&Qts[(ne * 16 + l15) * PITCH + ech];
            const bf16x8 qb1 = *(const bf16x8*)&Qts[(ne * 16 + l15) * PITCH + ech + 32];
            oacc[ne] = __builtin_amdgcn_mfma_f32_16x16x32_bf16(pa0, qb0, oacc[ne], 0, 0, 0);
            oacc[ne] = __builtin_amdgcn_mfma_f32_16x16x32_bf16(pa1, qb1, oacc[ne], 0, 0, 0);
        }
    }
    u16* dkb = dqkb + (size_t)b * 512 * C2 + DDIM + h * HDIM;
    #pragma unroll
    for (int r = 0; r < 4; ++r) {
        const int row = jt + wid * 16 + ((lane >> 4) << 2) + r;
        #pragma unroll
        for (int ne = 0; ne < 4; ++ne)
            dkb[(size_t)row * C2 + ne * 16 + l15] = f2bf(oacc[ne][r]);
    }
}

// ---------------------------------------------------------------------------
// LN backward + gradient step (fp32).
// ---------------------------------------------------------------------------
__global__ __launch_bounds__(256) void ln_bwd_update(const float* __restrict__ G,
                                                     const float* __restrict__ xhat,
                                                     const float* __restrict__ rstd,
                                                     const float* __restrict__ gamma,
                                                     const float* __restrict__ xin,
                                                     float* __restrict__ xout) {
    const int row = blockIdx.x;
    const int tid = threadIdx.x;
    const float* Gr = G    + (size_t)row * DDIM;
    const float* xh = xhat + (size_t)row * DDIM;
    float dxh[3], xhv[3];
    float s1 = 0.f, s2 = 0.f;
    #pragma unroll
    for (int c = 0; c < 3; ++c) {
        const int d = tid + c * 256;
        dxh[c] = gamma[d] * Gr[d];
        xhv[c] = xh[d];
        s1 += dxh[c];
        s2 += dxh[c] * xhv[c];
    }
    __shared__ float sb1[4], sb2[4];
    for (int off = 32; off > 0; off >>= 1) {
        s1 += __shfl_down(s1, off, 64);
        s2 += __shfl_down(s2, off, 64);
    }
    const int lane = tid & 63, wid = tid >> 6;
    if (lane == 0) { sb1[wid] = s1; sb2[wid] = s2; }
    __syncthreads();
    s1 = sb1[0] + sb1[1] + sb1[2] + sb1[3];
    s2 = sb2[0] + sb2[1] + sb2[2] + sb2[3];
    const float rs = rstd[row];
    const float m1 = s1 * (1.0f / DDIM);
    const float m2 = s2 * (1.0f / DDIM);
    #pragma unroll
    for (int c = 0; c < 3; ++c) {
        const int d = tid + c * 256;
        const float dx = rs * (dxh[c] - m1 - xhv[c] * m2);
        xout[(size_t)row * DDIM + d] = xin[(size_t)row * DDIM + d] + ALPHA * dx;
    }
}

// ---------------------------------------------------------------------------
extern "C" void kernel_launch(void* const* d_in, const int* in_sizes, int n_in,
                              void* d_out, int out_size, void* d_ws, size_t ws_size,
                              hipStream_t stream) {
    (void)in_sizes; (void)n_in; (void)out_size; (void)ws_size;
    const float* x     = (const float*)d_in[0];
    const float* gamma = (const float*)d_in[1];
    const float* delta = (const float*)d_in[2];
    const float* Wq    = (const float*)d_in[3];
    const float* Wk    = (const float*)d_in[4];
    const float* xi    = (const float*)d_in[5];
    float* out = (float*)d_out;

    // workspace layout (~56 MB)
    char* p = (char*)d_ws;
    u16* gb   = (u16*)p;  p += (size_t)NTOK * DDIM * 2;   // bf16 g
    u16* Rb   = (u16*)p;  p += (size_t)NTOK * MMEM * 2;   // bf16 relu(g xi^T)
    u16* qkb  = (u16*)p;  p += (size_t)NTOK * C2   * 2;   // bf16 q||k
    u16* dqkb = (u16*)p;  p += (size_t)NTOK * C2   * 2;   // bf16 dq||dk
    u16* xib  = (u16*)p;  p += (size_t)MMEM * DDIM * 2;   // bf16 xi
    u16* xibT = (u16*)p;  p += (size_t)DDIM * MMEM * 2;   // bf16 xi^T
    u16* Pb   = (u16*)p;  p += (size_t)DDIM * C2   * 2;   // bf16 P  [768][1536]
    u16* PTb  = (u16*)p;  p += (size_t)C2   * DDIM * 2;   // bf16 P^T[1536][768]
    float* xhat = (float*)p; p += (size_t)NTOK * DDIM * 4;
    float* dg   = (float*)p; p += (size_t)NTOK * DDIM * 4;
    float* rstd = (float*)p; p += (size_t)NTOK * 4;
    float* lse  = (float*)p;

    // operand prep (repeated every launch for graph-capture safety)
    conv_xi<<<dim3(12, 48), dim3(256), 0, stream>>>(xi, xib, xibT);
    conv_p <<<dim3(DDIM, 6), dim3(256), 0, stream>>>(Wq, Wk, Pb);
    conv_pT<<<dim3(12, 24), dim3(256), 0, stream>>>(Wq, Wk, PTb);

    for (int s = 0; s < NSTEPS; ++s) {
        const float* xs = (s == 0) ? x : out;
        ln_fwd<<<dim3(NTOK), dim3(256), 0, stream>>>(xs, gamma, delta, gb, xhat, rstd);
        // Hopfield: Rb = bf16(relu(gb xi^T)); dg = Rb @ xi
        gemm_bf<0><<<dim3(MMEM / 128, NTOK / 128), dim3(256), 0, stream>>>(
            gb, xib, nullptr, Rb, DDIM, MMEM);
        gemm_bf<1><<<dim3(DDIM / 128, NTOK / 128), dim3(256), 0, stream>>>(
            Rb, xibT, dg, nullptr, MMEM, DDIM);
        // Attention: qkb = bf16(gb @ P), MFMA flash dq/dk, dg += dqkb @ P^T
        gemm_bf<3><<<dim3(C2 / 128, NTOK / 128), dim3(256), 0, stream>>>(
            gb, PTb, nullptr, qkb, DDIM, C2);
        attn_dq_mf<<<dim3(8, NHEAD, 4), dim3(256), 0, stream>>>(qkb, dqkb, lse);
        attn_dk_mf<<<dim3(8, NHEAD, 4), dim3(256), 0, stream>>>(qkb, dqkb, lse);
        gemm_bf<2><<<dim3(DDIM / 128, NTOK / 128), dim3(256), 0, stream>>>(
            dqkb, Pb, dg, nullptr, C2, DDIM);
        // LN backward + step
        ln_bwd_update<<<dim3(NTOK), dim3(256), 0, stream>>>(
            dg, xhat, rstd, gamma, xs, out);
    }
}